// Round 4
// baseline (2096.845 us; speedup 1.0000x reference)
//
#include <hip/hip_runtime.h>
#include <math.h>

// Problem constants (B,T,N,D) = (2,64,512,256)
#define B_ 2
#define T_ 64
#define N_ 512
#define D_ 256
#define M_ (B_*T_*N_)            // 65536 rows for the GEMMs
#define PLANE ((size_t)M_*D_)    // 16777216 elements per output plane

typedef unsigned short u16;
typedef __attribute__((ext_vector_type(8))) short bf16x8;
typedef __attribute__((ext_vector_type(4))) float f32x4;

__device__ __forceinline__ u16 f2bf(float f) {
  union { float f; unsigned u; } cv; cv.f = f;
  unsigned u = cv.u;
  return (u16)((u + 0x7FFFu + ((u >> 16) & 1u)) >> 16);   // RNE
}
__device__ __forceinline__ float bf2f(u16 h) {
  union { unsigned u; float f; } cv; cv.u = ((unsigned)h) << 16;
  return cv.f;
}

// ---------------------------------------------------------------------------
// A init: col-major float2 A[c*256+r] = raw[r][c]
// ---------------------------------------------------------------------------
__global__ __launch_bounds__(1024) void qr_init_kernel(
    const float* __restrict__ ure_raw, const float* __restrict__ uim_raw,
    float2* __restrict__ A)
{
  int i = blockIdx.x * 1024 + threadIdx.x;   // 64 blocks
  int c = i >> 8, r = i & 255;
  A[i] = make_float2(ure_raw[r*D_ + c], uim_raw[r*D_ + c]);
}

// ---------------------------------------------------------------------------
// Panel factorization (zgeqr2 on cols j0..j0+31, rows j0..255), LAPACK
// convention, fp32. 256 threads = 4 waves; wave w owns cols {w, w+4, ...}
// of the panel, each column in 4 float2 registers per lane. v broadcast via
// LDS. Numerically identical reflector sequence to the unblocked version.
// ---------------------------------------------------------------------------
__global__ __launch_bounds__(256) void qr_panel_kernel(
    float2* __restrict__ A, float2* __restrict__ tau, int j0)
{
  const int tid = threadIdx.x, lane = tid & 63, w = tid >> 6;
  const int R = 256 - j0;
  __shared__ float2 sv[256];
  __shared__ float2 stau;
  float2 col[8][4];

  #pragma unroll
  for (int lc = 0; lc < 8; ++lc) {
    int cg = j0 + lc*4 + w;
    #pragma unroll
    for (int m = 0; m < 4; ++m) {
      int rr = m*64 + lane;
      col[lc][m] = (rr < R) ? A[cg*D_ + j0 + rr] : make_float2(0.f, 0.f);
    }
  }

  for (int jl = 0; jl < 32; ++jl) {
    const int wo = jl & 3, ljc = jl >> 2;
    if (w == wo) {
      float2 dcol[4];
      #pragma unroll
      for (int lc = 0; lc < 8; ++lc)
        if (lc == ljc) { dcol[0]=col[lc][0]; dcol[1]=col[lc][1];
                         dcol[2]=col[lc][2]; dcol[3]=col[lc][3]; }
      float part = 0.f;
      #pragma unroll
      for (int m = 0; m < 4; ++m) {
        int rr = m*64 + lane;
        if (rr > jl && rr < R) part += dcol[m].x*dcol[m].x + dcol[m].y*dcol[m].y;
      }
      #pragma unroll
      for (int s = 32; s; s >>= 1) part += __shfl_xor(part, s);
      float ar = __shfl(dcol[0].x, jl), ai = __shfl(dcol[0].y, jl);
      float taur, taui, sclr, scli;
      if (part == 0.f && ai == 0.f) {
        taur = taui = sclr = scli = 0.f;
      } else {
        float nrm  = sqrtf(ar*ar + ai*ai + part);
        float beta = (ar >= 0.f) ? -nrm : nrm;     // -SIGN(nrm, Re(alpha))
        taur = (beta - ar)/beta; taui = -ai/beta;
        float dr = ar - beta, di = ai, dn = dr*dr + di*di;
        sclr = dr/dn; scli = -di/dn;               // 1/(alpha-beta)
      }
      #pragma unroll
      for (int m = 0; m < 4; ++m) {
        int rr = m*64 + lane;
        float2 a = dcol[m], v;
        if (rr > jl)      v = make_float2(a.x*sclr - a.y*scli, a.x*scli + a.y*sclr);
        else if (rr == jl) v = make_float2(1.f, 0.f);
        else              v = make_float2(0.f, 0.f);
        dcol[m] = v;
        sv[rr] = v;
      }
      #pragma unroll
      for (int lc = 0; lc < 8; ++lc)
        if (lc == ljc) { col[lc][0]=dcol[0]; col[lc][1]=dcol[1];
                         col[lc][2]=dcol[2]; col[lc][3]=dcol[3]; }
      if (lane == 0) { stau = make_float2(taur, taui);
                       tau[j0+jl] = make_float2(taur, taui); }
    }
    __syncthreads();
    const float taur = stau.x, taui = stau.y;
    float2 v[4];
    #pragma unroll
    for (int m = 0; m < 4; ++m) v[m] = sv[m*64 + lane];
    float wr[8], wi[8];
    #pragma unroll
    for (int lc = 0; lc < 8; ++lc) {
      int cl = lc*4 + w;
      wr[lc] = 0.f; wi[lc] = 0.f;
      if (cl > jl) {
        #pragma unroll
        for (int m = 0; m < 4; ++m) {
          float2 a = col[lc][m];
          wr[lc] += v[m].x*a.x + v[m].y*a.y;     // w += conj(v)*a
          wi[lc] += v[m].x*a.y - v[m].y*a.x;
        }
      }
    }
    #pragma unroll
    for (int lc = 0; lc < 8; ++lc) {
      #pragma unroll
      for (int s = 32; s; s >>= 1) { wr[lc] += __shfl_xor(wr[lc], s);
                                     wi[lc] += __shfl_xor(wi[lc], s); }
    }
    #pragma unroll
    for (int lc = 0; lc < 8; ++lc) {
      int cl = lc*4 + w;
      if (cl > jl) {
        float fr = taur*wr[lc] + taui*wi[lc];    // f = conj(tau)*w
        float fi = taur*wi[lc] - taui*wr[lc];
        #pragma unroll
        for (int m = 0; m < 4; ++m) {
          col[lc][m].x -= fr*v[m].x - fi*v[m].y;
          col[lc][m].y -= fr*v[m].y + fi*v[m].x;
        }
      }
    }
    __syncthreads();
  }

  #pragma unroll
  for (int lc = 0; lc < 8; ++lc) {
    int cg = j0 + lc*4 + w;
    #pragma unroll
    for (int m = 0; m < 4; ++m) {
      int rr = m*64 + lane;
      if (rr < R) A[cg*D_ + j0 + rr] = col[lc][m];
    }
  }
}

// ---------------------------------------------------------------------------
// Apply panel j0's 32 reflectors to a 32-column trailing tile (registers).
// blockIdx.x selects the tile; v streamed from L2 per reflector per wave.
// f = conj(tau)*w; tau==0 degenerates to a no-op (f=0), no branch needed.
// ---------------------------------------------------------------------------
__global__ __launch_bounds__(256) void qr_apply_kernel(
    float2* __restrict__ A, const float2* __restrict__ tau, int j0)
{
  const int tid = threadIdx.x, lane = tid & 63, w = tid >> 6;
  const int R = 256 - j0;
  const int c0 = j0 + 32 + blockIdx.x * 32;
  float2 col[8][4];
  #pragma unroll
  for (int lc = 0; lc < 8; ++lc) {
    int cg = c0 + lc*4 + w;
    #pragma unroll
    for (int m = 0; m < 4; ++m) {
      int rr = m*64 + lane;
      col[lc][m] = (rr < R) ? A[cg*D_ + j0 + rr] : make_float2(0.f, 0.f);
    }
  }
  for (int jl = 0; jl < 32; ++jl) {
    float2 tt = tau[j0 + jl];
    float2 v[4];
    #pragma unroll
    for (int m = 0; m < 4; ++m) {
      int rr = m*64 + lane;
      float2 raw = (rr < R) ? A[(j0+jl)*D_ + j0 + rr] : make_float2(0.f, 0.f);
      v[m] = (rr > jl) ? raw
           : ((rr == jl) ? make_float2(1.f, 0.f) : make_float2(0.f, 0.f));
    }
    float wr[8], wi[8];
    #pragma unroll
    for (int lc = 0; lc < 8; ++lc) {
      wr[lc] = 0.f; wi[lc] = 0.f;
      #pragma unroll
      for (int m = 0; m < 4; ++m) {
        float2 a = col[lc][m];
        wr[lc] += v[m].x*a.x + v[m].y*a.y;
        wi[lc] += v[m].x*a.y - v[m].y*a.x;
      }
    }
    #pragma unroll
    for (int lc = 0; lc < 8; ++lc) {
      #pragma unroll
      for (int s = 32; s; s >>= 1) { wr[lc] += __shfl_xor(wr[lc], s);
                                     wi[lc] += __shfl_xor(wi[lc], s); }
    }
    #pragma unroll
    for (int lc = 0; lc < 8; ++lc) {
      float fr = tt.x*wr[lc] + tt.y*wi[lc];
      float fi = tt.x*wi[lc] - tt.y*wr[lc];
      #pragma unroll
      for (int m = 0; m < 4; ++m) {
        col[lc][m].x -= fr*v[m].x - fi*v[m].y;
        col[lc][m].y -= fr*v[m].y + fi*v[m].x;
      }
    }
  }
  #pragma unroll
  for (int lc = 0; lc < 8; ++lc) {
    int cg = c0 + lc*4 + w;
    #pragma unroll
    for (int m = 0; m < 4; ++m) {
      int rr = m*64 + lane;
      if (rr < R) A[cg*D_ + j0 + rr] = col[lc][m];
    }
  }
}

// ---------------------------------------------------------------------------
// zung2r, blocked: ONE launch, 8 blocks. Block b holds Q-columns 32b..32b+31
// in registers (8 cols/wave x 4 row-chunks) and applies reflectors
// i = 32b+31 .. 0 in DESCENDING order. For a column c, any reflector i > c
// yields w == 0 exactly (v[r]=0 for r<i while q=e_c), so no branch is needed;
// reflectors above the block's top column are skipped entirely.
// Epilogue writes the bf16 B^T matrices for both GEMMs:
//   Benc [512][256]: rows 0..255 = Re(Q)^T, rows 256.. = Im(Q)^T
//   Bdec [512][512]: [n][k]: n<256,k<256: ur[k][n]; n<256,k>=256: -ui
//                    n>=256,k<256: ui;             n>=256,k>=256: ur
// ---------------------------------------------------------------------------
__global__ __launch_bounds__(256) void qr_bwd_kernel(
    const float2* __restrict__ A, const float2* __restrict__ tau,
    u16* __restrict__ Benc, u16* __restrict__ Bdec)
{
  const int lane = threadIdx.x & 63, w = threadIdx.x >> 6;
  const int c0 = blockIdx.x * 32;
  __shared__ float2 stau[256];
  if (threadIdx.x < 256) stau[threadIdx.x] = tau[threadIdx.x];
  __syncthreads();

  float2 q[8][4];
  #pragma unroll
  for (int lc = 0; lc < 8; ++lc) {
    int cg = c0 + lc*4 + w;
    #pragma unroll
    for (int m = 0; m < 4; ++m) {
      q[lc][m] = make_float2(0.f, 0.f);
      if (m*64 + lane == cg) q[lc][m].x = 1.f;
    }
  }

  for (int i = c0 + 31; i >= 0; --i) {
    float2 tt = stau[i];
    if (tt.x == 0.f && tt.y == 0.f) continue;    // wave-uniform
    float2 v[4];
    #pragma unroll
    for (int m = 0; m < 4; ++m) {
      int r = m*64 + lane;
      float2 a = A[i*D_ + r];
      v[m] = (r > i) ? a : ((r == i) ? make_float2(1.f, 0.f)
                                     : make_float2(0.f, 0.f));
    }
    float wr[8], wi[8];
    #pragma unroll
    for (int lc = 0; lc < 8; ++lc) {
      wr[lc] = 0.f; wi[lc] = 0.f;
      #pragma unroll
      for (int m = 0; m < 4; ++m) {
        float2 qq = q[lc][m];
        wr[lc] += v[m].x*qq.x + v[m].y*qq.y;     // w += conj(v)*q
        wi[lc] += v[m].x*qq.y - v[m].y*qq.x;
      }
    }
    #pragma unroll
    for (int lc = 0; lc < 8; ++lc) {
      #pragma unroll
      for (int s = 32; s; s >>= 1) { wr[lc] += __shfl_xor(wr[lc], s);
                                     wi[lc] += __shfl_xor(wi[lc], s); }
    }
    #pragma unroll
    for (int lc = 0; lc < 8; ++lc) {
      float fr = tt.x*wr[lc] - tt.y*wi[lc];      // f = tau*w
      float fi = tt.x*wi[lc] + tt.y*wr[lc];
      #pragma unroll
      for (int m = 0; m < 4; ++m) {
        q[lc][m].x -= fr*v[m].x - fi*v[m].y;
        q[lc][m].y -= fr*v[m].y + fi*v[m].x;
      }
    }
  }

  #pragma unroll
  for (int lc = 0; lc < 8; ++lc) {
    int c = c0 + lc*4 + w;
    #pragma unroll
    for (int m = 0; m < 4; ++m) {
      int r = m*64 + lane;
      u16 qre = f2bf(q[lc][m].x), qim = f2bf(q[lc][m].y), qimn = f2bf(-q[lc][m].y);
      Benc[(size_t)c*D_ + r]              = qre;
      Benc[(size_t)(c+256)*D_ + r]        = qim;
      Bdec[(size_t)c*512 + r]             = qre;
      Bdec[(size_t)c*512 + 256 + r]       = qimn;
      Bdec[(size_t)(c+256)*512 + r]       = qim;
      Bdec[(size_t)(c+256)*512 + 256 + r] = qre;
    }
  }
}

// ---------------------------------------------------------------------------
// x fp32 -> bf16
// ---------------------------------------------------------------------------
__global__ __launch_bounds__(256) void xconv_kernel(
    const float4* __restrict__ x, ushort4* __restrict__ x16)
{
  const size_t n4 = PLANE/4;
  for (size_t i = blockIdx.x*256 + threadIdx.x; i < n4; i += (size_t)2048*256) {
    float4 v = x[i];
    ushort4 o;
    o.x = f2bf(v.x); o.y = f2bf(v.y); o.z = f2bf(v.z); o.w = f2bf(v.w);
    x16[i] = o;
  }
}

// ---------------------------------------------------------------------------
// bf16 MFMA GEMM, 128x128 tile, 4 waves, BK=64, 16x16x32 MFMA.
// A [M][K] bf16 row-major (1 or 2 planes), B supplied transposed [N][K].
// LDS row stride 72 elements (144 B): 16B-aligned, 2-way banks (free).
// ---------------------------------------------------------------------------
#define LDT 72

__global__ __launch_bounds__(256) void encode_gemm(
    const u16* __restrict__ x16, const u16* __restrict__ Bt,
    u16* __restrict__ xer16, u16* __restrict__ xei16)
{
  __shared__ u16 sA[128*LDT];
  __shared__ u16 sB[128*LDT];
  const int tid = threadIdx.x;
  const int lane = tid & 63, w = tid >> 6;
  const int wr = w >> 1, wc = w & 1;
  const int l15 = lane & 15, l4 = lane >> 4;
  const int m0 = blockIdx.x * 128;
  const int n0 = blockIdx.y * 128;
  f32x4 acc[4][4] = {};
  for (int kb = 0; kb < 4; ++kb) {
    #pragma unroll
    for (int i = 0; i < 4; ++i) {
      int chunk = i*256 + tid;
      int row = chunk >> 3, k0 = (chunk & 7) * 8;
      int4 va = *(const int4*)(x16 + (size_t)(m0+row)*D_ + kb*64 + k0);
      int4 vb = *(const int4*)(Bt  + (size_t)(n0+row)*D_ + kb*64 + k0);
      *(int4*)&sA[row*LDT + k0] = va;
      *(int4*)&sB[row*LDT + k0] = vb;
    }
    __syncthreads();
    #pragma unroll
    for (int ks = 0; ks < 2; ++ks) {
      bf16x8 af[4], bb[4];
      #pragma unroll
      for (int mf = 0; mf < 4; ++mf)
        af[mf] = *(const bf16x8*)&sA[(wr*64 + mf*16 + l15)*LDT + ks*32 + l4*8];
      #pragma unroll
      for (int nf = 0; nf < 4; ++nf)
        bb[nf] = *(const bf16x8*)&sB[(wc*64 + nf*16 + l15)*LDT + ks*32 + l4*8];
      #pragma unroll
      for (int mf = 0; mf < 4; ++mf)
        #pragma unroll
        for (int nf = 0; nf < 4; ++nf)
          acc[mf][nf] = __builtin_amdgcn_mfma_f32_16x16x32_bf16(
              af[mf], bb[nf], acc[mf][nf], 0, 0, 0);
    }
    __syncthreads();
  }
  #pragma unroll
  for (int mf = 0; mf < 4; ++mf)
    #pragma unroll
    for (int nf = 0; nf < 4; ++nf)
      #pragma unroll
      for (int r = 0; r < 4; ++r) {
        int row = m0 + wr*64 + mf*16 + l4*4 + r;
        int col = n0 + wc*64 + nf*16 + l15;
        float v = acc[mf][nf][r];
        if (col < 256) xer16[(size_t)row*D_ + col] = f2bf(v);
        else           xei16[(size_t)row*D_ + col - 256] = f2bf(-v);
      }
}

__global__ __launch_bounds__(256) void decode_gemm(
    const u16* __restrict__ hre16, const u16* __restrict__ him16,
    const u16* __restrict__ Bt, float* __restrict__ out)
{
  __shared__ u16 sA[128*LDT];
  __shared__ u16 sB[128*LDT];
  const int tid = threadIdx.x;
  const int lane = tid & 63, w = tid >> 6;
  const int wr = w >> 1, wc = w & 1;
  const int l15 = lane & 15, l4 = lane >> 4;
  const int m0 = blockIdx.x * 128;
  const int n0 = blockIdx.y * 128;
  f32x4 acc[4][4] = {};
  for (int kb = 0; kb < 8; ++kb) {
    const u16* aplane = (kb < 4) ? hre16 : him16;
    const int kk = (kb & 3) * 64;
    #pragma unroll
    for (int i = 0; i < 4; ++i) {
      int chunk = i*256 + tid;
      int row = chunk >> 3, k0 = (chunk & 7) * 8;
      int4 va = *(const int4*)(aplane + (size_t)(m0+row)*D_ + kk + k0);
      int4 vb = *(const int4*)(Bt + (size_t)(n0+row)*512 + kb*64 + k0);
      *(int4*)&sA[row*LDT + k0] = va;
      *(int4*)&sB[row*LDT + k0] = vb;
    }
    __syncthreads();
    #pragma unroll
    for (int ks = 0; ks < 2; ++ks) {
      bf16x8 af[4], bb[4];
      #pragma unroll
      for (int mf = 0; mf < 4; ++mf)
        af[mf] = *(const bf16x8*)&sA[(wr*64 + mf*16 + l15)*LDT + ks*32 + l4*8];
      #pragma unroll
      for (int nf = 0; nf < 4; ++nf)
        bb[nf] = *(const bf16x8*)&sB[(wc*64 + nf*16 + l15)*LDT + ks*32 + l4*8];
      #pragma unroll
      for (int mf = 0; mf < 4; ++mf)
        #pragma unroll
        for (int nf = 0; nf < 4; ++nf)
          acc[mf][nf] = __builtin_amdgcn_mfma_f32_16x16x32_bf16(
              af[mf], bb[nf], acc[mf][nf], 0, 0, 0);
    }
    __syncthreads();
  }
  #pragma unroll
  for (int mf = 0; mf < 4; ++mf)
    #pragma unroll
    for (int nf = 0; nf < 4; ++nf)
      #pragma unroll
      for (int r = 0; r < 4; ++r) {
        int row = m0 + wr*64 + mf*16 + l4*4 + r;
        int col = n0 + wc*64 + nf*16 + l15;
        float v = acc[mf][nf][r];
        if (col < 256) out[(size_t)row*D_ + col] = v;
        else           out[PLANE + (size_t)row*D_ + col - 256] = v;
      }
}

// ---------------------------------------------------------------------------
// Scan with fused coefficient computation. One block per (b,n); thread = d.
// Per-thread t-invariant parts hoisted; per-t: exp, sincos, sqrt (hidden
// under HBM traffic at 4096 waves).
// ---------------------------------------------------------------------------
__global__ __launch_bounds__(256) void scan_kernel(
  const float* __restrict__ eps, const float* __restrict__ dt,
  const float* __restrict__ lam_re, const float* __restrict__ lam_im,
  const float* __restrict__ noise_raw,
  const u16* __restrict__ xer16, const u16* __restrict__ xei16,
  u16* __restrict__ hre16, u16* __restrict__ him16)
{
  int bx = blockIdx.x;
  int b = bx >> 9, n = bx & 511;
  int d = threadIdx.x;
  __shared__ float sdt[T_];
  if (d < T_) sdt[d] = dt[b*T_ + d];
  __syncthreads();

  float lr = lam_re[d], li = lam_im[d];
  float lam_r = fmaxf(-log1pf(expf(-lr)), -0.3f);     // -softplus(-x), clamp
  float t0 = lam_r + 1e-12f;
  float sgn = (t0 > 0.f) ? 1.f : ((t0 < 0.f) ? -1.f : 0.f);
  float den_re = lam_r + 1e-8f*sgn, den_im = li;      // lam_safe
  float d2 = den_re*den_re + den_im*den_im;
  float nsc = log1pf(expf(noise_raw[d])) * 0.01f;

  float hr = 0.f, hi = 0.f;
  for (int t = 0; t < T_; ++t) {
    float dtv = sdt[t];
    float er = expf(dtv*lam_r);
    float ai = dtv*li;
    float dre = er*cosf(ai), dim_ = er*sinf(ai);
    float nr = dre - 1.f, ni = dim_;
    float fre = (nr*den_re + ni*den_im)/d2;
    float fim = (ni*den_re - nr*den_im)/d2;
    float ns = sqrtf(fmaxf(dtv, 0.f)) * nsc;
    size_t idx = ((size_t)(b*T_ + t)*N_ + n)*D_ + d;
    float xr = bf2f(xer16[idx]), xi = bf2f(xei16[idx]), ep = eps[idx];
    float br = fre*xr - fim*xi + ep*ns;
    float bi = fre*xi + fim*xr;
    float nr2 = dre*hr - dim_*hi + br;
    float ni2 = dre*hi + dim_*hr + bi;
    hr = nr2; hi = ni2;
    hre16[idx] = f2bf(hr); him16[idx] = f2bf(hi);
  }
}

// ---------------------------------------------------------------------------
extern "C" void kernel_launch(void* const* d_in, const int* in_sizes, int n_in,
                              void* d_out, int out_size, void* d_ws, size_t ws_size,
                              hipStream_t stream)
{
  const float* x         = (const float*)d_in[0];
  const float* dt        = (const float*)d_in[1];
  const float* eps       = (const float*)d_in[2];
  const float* ure_raw   = (const float*)d_in[3];
  const float* uim_raw   = (const float*)d_in[4];
  const float* lam_re    = (const float*)d_in[5];
  const float* lam_im    = (const float*)d_in[6];
  const float* noise_raw = (const float*)d_in[7];
  float* out = (float*)d_out;

  // ws layout (132 MB total):
  //   0       A float2[65536]            512 KB
  //   512K    tau float2[256]
  //   1M      Benc bf16 [512][256]       256 KB
  //   1.5M    Bdec bf16 [512][512]       512 KB
  //   4M      x16 bf16 [M][256]  32 MB   (reused as hre16 after encode)
  //   36M     xer16 32 MB
  //   68M     xei16 32 MB
  //   100M    him16 32 MB
  char* ws = (char*)d_ws;
  float2* A    = (float2*)(ws);
  float2* tau  = (float2*)(ws + 524288);
  u16* Benc    = (u16*)(ws + (1<<20));
  u16* Bdec    = (u16*)(ws + 1572864);
  u16* x16     = (u16*)(ws + ((size_t)4<<20));
  u16* xer16   = (u16*)(ws + ((size_t)36<<20));
  u16* xei16   = (u16*)(ws + ((size_t)68<<20));
  u16* hre16   = x16;
  u16* him16   = (u16*)(ws + ((size_t)100<<20));

  qr_init_kernel<<<64, 1024, 0, stream>>>(ure_raw, uim_raw, A);
  for (int p = 0; p < 8; ++p) {
    qr_panel_kernel<<<1, 256, 0, stream>>>(A, tau, 32*p);
    int nb = 7 - p;
    if (nb > 0) qr_apply_kernel<<<nb, 256, 0, stream>>>(A, tau, 32*p);
  }
  qr_bwd_kernel<<<8, 256, 0, stream>>>(A, tau, Benc, Bdec);
  xconv_kernel<<<2048, 256, 0, stream>>>((const float4*)x, (ushort4*)x16);
  encode_gemm<<<dim3(M_/128, 4), 256, 0, stream>>>(x16, Benc, xer16, xei16);
  scan_kernel<<<B_*N_, 256, 0, stream>>>(eps, dt, lam_re, lam_im, noise_raw,
                                         xer16, xei16, hre16, him16);
  decode_gemm<<<dim3(M_/128, 4), 256, 0, stream>>>(hre16, him16, Bdec, out);
}

// Round 5
// 1545.406 us; speedup vs baseline: 1.3568x; 1.3568x over previous
//
#include <hip/hip_runtime.h>
#include <math.h>

// Problem constants (B,T,N,D) = (2,64,512,256)
#define B_ 2
#define T_ 64
#define N_ 512
#define D_ 256
#define M_ (B_*T_*N_)            // 65536 rows for the GEMMs
#define PLANE ((size_t)M_*D_)    // 16777216 elements per output plane

typedef unsigned short u16;
typedef __attribute__((ext_vector_type(8))) short bf16x8;
typedef __attribute__((ext_vector_type(4))) float f32x4;

__device__ __forceinline__ u16 f2bf(float f) {
  union { float f; unsigned u; } cv; cv.f = f;
  unsigned u = cv.u;
  return (u16)((u + 0x7FFFu + ((u >> 16) & 1u)) >> 16);   // RNE
}
__device__ __forceinline__ float bf2f(u16 h) {
  union { unsigned u; float f; } cv; cv.u = ((unsigned)h) << 16;
  return cv.f;
}

// ---------------------------------------------------------------------------
// A init: col-major float2 A[c*256+r] = raw[r][c]
// ---------------------------------------------------------------------------
__global__ __launch_bounds__(1024) void qr_init_kernel(
    const float* __restrict__ ure_raw, const float* __restrict__ uim_raw,
    float2* __restrict__ A)
{
  int i = blockIdx.x * 1024 + threadIdx.x;   // 64 blocks
  int c = i >> 8, r = i & 255;
  A[i] = make_float2(ure_raw[r*D_ + c], uim_raw[r*D_ + c]);
}

// ---------------------------------------------------------------------------
// Panel factorization (zgeqr2 on cols j0..j0+31, rows j0..255), LAPACK
// convention, fp32. 256 threads = 4 waves; wave w owns cols {w, w+4, ...}
// of the panel, each column in 4 float2 registers per lane. v broadcast via
// LDS. Numerically identical reflector sequence to the unblocked version.
// __launch_bounds__(256,1): needs ~120 VGPRs; default cap of 64 spilled
// the register-resident panel to scratch (round-4 post-mortem).
// ---------------------------------------------------------------------------
__global__ __launch_bounds__(256, 1) void qr_panel_kernel(
    float2* __restrict__ A, float2* __restrict__ tau, int j0)
{
  const int tid = threadIdx.x, lane = tid & 63, w = tid >> 6;
  const int R = 256 - j0;
  __shared__ float2 sv[256];
  __shared__ float2 stau;
  float2 col[8][4];

  #pragma unroll
  for (int lc = 0; lc < 8; ++lc) {
    int cg = j0 + lc*4 + w;
    #pragma unroll
    for (int m = 0; m < 4; ++m) {
      int rr = m*64 + lane;
      col[lc][m] = (rr < R) ? A[cg*D_ + j0 + rr] : make_float2(0.f, 0.f);
    }
  }

  for (int jl = 0; jl < 32; ++jl) {
    const int wo = jl & 3, ljc = jl >> 2;
    if (w == wo) {
      float2 dcol[4];
      #pragma unroll
      for (int lc = 0; lc < 8; ++lc)
        if (lc == ljc) { dcol[0]=col[lc][0]; dcol[1]=col[lc][1];
                         dcol[2]=col[lc][2]; dcol[3]=col[lc][3]; }
      float part = 0.f;
      #pragma unroll
      for (int m = 0; m < 4; ++m) {
        int rr = m*64 + lane;
        if (rr > jl && rr < R) part += dcol[m].x*dcol[m].x + dcol[m].y*dcol[m].y;
      }
      #pragma unroll
      for (int s = 32; s; s >>= 1) part += __shfl_xor(part, s);
      float ar = __shfl(dcol[0].x, jl), ai = __shfl(dcol[0].y, jl);
      float taur, taui, sclr, scli;
      if (part == 0.f && ai == 0.f) {
        taur = taui = sclr = scli = 0.f;
      } else {
        float nrm  = sqrtf(ar*ar + ai*ai + part);
        float beta = (ar >= 0.f) ? -nrm : nrm;     // -SIGN(nrm, Re(alpha))
        taur = (beta - ar)/beta; taui = -ai/beta;
        float dr = ar - beta, di = ai, dn = dr*dr + di*di;
        sclr = dr/dn; scli = -di/dn;               // 1/(alpha-beta)
      }
      #pragma unroll
      for (int m = 0; m < 4; ++m) {
        int rr = m*64 + lane;
        float2 a = dcol[m], v;
        if (rr > jl)      v = make_float2(a.x*sclr - a.y*scli, a.x*scli + a.y*sclr);
        else if (rr == jl) v = make_float2(1.f, 0.f);
        else              v = make_float2(0.f, 0.f);
        dcol[m] = v;
        sv[rr] = v;
      }
      #pragma unroll
      for (int lc = 0; lc < 8; ++lc)
        if (lc == ljc) { col[lc][0]=dcol[0]; col[lc][1]=dcol[1];
                         col[lc][2]=dcol[2]; col[lc][3]=dcol[3]; }
      if (lane == 0) { stau = make_float2(taur, taui);
                       tau[j0+jl] = make_float2(taur, taui); }
    }
    __syncthreads();
    const float taur = stau.x, taui = stau.y;
    float2 v[4];
    #pragma unroll
    for (int m = 0; m < 4; ++m) v[m] = sv[m*64 + lane];
    float wr[8], wi[8];
    #pragma unroll
    for (int lc = 0; lc < 8; ++lc) {
      int cl = lc*4 + w;
      wr[lc] = 0.f; wi[lc] = 0.f;
      if (cl > jl) {
        #pragma unroll
        for (int m = 0; m < 4; ++m) {
          float2 a = col[lc][m];
          wr[lc] += v[m].x*a.x + v[m].y*a.y;     // w += conj(v)*a
          wi[lc] += v[m].x*a.y - v[m].y*a.x;
        }
      }
    }
    #pragma unroll
    for (int lc = 0; lc < 8; ++lc) {
      #pragma unroll
      for (int s = 32; s; s >>= 1) { wr[lc] += __shfl_xor(wr[lc], s);
                                     wi[lc] += __shfl_xor(wi[lc], s); }
    }
    #pragma unroll
    for (int lc = 0; lc < 8; ++lc) {
      int cl = lc*4 + w;
      if (cl > jl) {
        float fr = taur*wr[lc] + taui*wi[lc];    // f = conj(tau)*w
        float fi = taur*wi[lc] - taui*wr[lc];
        #pragma unroll
        for (int m = 0; m < 4; ++m) {
          col[lc][m].x -= fr*v[m].x - fi*v[m].y;
          col[lc][m].y -= fr*v[m].y + fi*v[m].x;
        }
      }
    }
    __syncthreads();
  }

  #pragma unroll
  for (int lc = 0; lc < 8; ++lc) {
    int cg = j0 + lc*4 + w;
    #pragma unroll
    for (int m = 0; m < 4; ++m) {
      int rr = m*64 + lane;
      if (rr < R) A[cg*D_ + j0 + rr] = col[lc][m];
    }
  }
}

// ---------------------------------------------------------------------------
// Apply panel j0's 32 reflectors to a 32-column trailing tile (registers).
// blockIdx.x selects the tile; v streamed from L2 per reflector per wave.
// f = conj(tau)*w; tau==0 degenerates to a no-op (f=0), no branch needed.
// __launch_bounds__(256,1): same spill fix as the panel.
// ---------------------------------------------------------------------------
__global__ __launch_bounds__(256, 1) void qr_apply_kernel(
    float2* __restrict__ A, const float2* __restrict__ tau, int j0)
{
  const int tid = threadIdx.x, lane = tid & 63, w = tid >> 6;
  const int R = 256 - j0;
  const int c0 = j0 + 32 + blockIdx.x * 32;
  float2 col[8][4];
  #pragma unroll
  for (int lc = 0; lc < 8; ++lc) {
    int cg = c0 + lc*4 + w;
    #pragma unroll
    for (int m = 0; m < 4; ++m) {
      int rr = m*64 + lane;
      col[lc][m] = (rr < R) ? A[cg*D_ + j0 + rr] : make_float2(0.f, 0.f);
    }
  }
  for (int jl = 0; jl < 32; ++jl) {
    float2 tt = tau[j0 + jl];
    float2 v[4];
    #pragma unroll
    for (int m = 0; m < 4; ++m) {
      int rr = m*64 + lane;
      float2 raw = (rr < R) ? A[(j0+jl)*D_ + j0 + rr] : make_float2(0.f, 0.f);
      v[m] = (rr > jl) ? raw
           : ((rr == jl) ? make_float2(1.f, 0.f) : make_float2(0.f, 0.f));
    }
    float wr[8], wi[8];
    #pragma unroll
    for (int lc = 0; lc < 8; ++lc) {
      wr[lc] = 0.f; wi[lc] = 0.f;
      #pragma unroll
      for (int m = 0; m < 4; ++m) {
        float2 a = col[lc][m];
        wr[lc] += v[m].x*a.x + v[m].y*a.y;
        wi[lc] += v[m].x*a.y - v[m].y*a.x;
      }
    }
    #pragma unroll
    for (int lc = 0; lc < 8; ++lc) {
      #pragma unroll
      for (int s = 32; s; s >>= 1) { wr[lc] += __shfl_xor(wr[lc], s);
                                     wi[lc] += __shfl_xor(wi[lc], s); }
    }
    #pragma unroll
    for (int lc = 0; lc < 8; ++lc) {
      float fr = tt.x*wr[lc] + tt.y*wi[lc];
      float fi = tt.x*wi[lc] - tt.y*wr[lc];
      #pragma unroll
      for (int m = 0; m < 4; ++m) {
        col[lc][m].x -= fr*v[m].x - fi*v[m].y;
        col[lc][m].y -= fr*v[m].y + fi*v[m].x;
      }
    }
  }
  #pragma unroll
  for (int lc = 0; lc < 8; ++lc) {
    int cg = c0 + lc*4 + w;
    #pragma unroll
    for (int m = 0; m < 4; ++m) {
      int rr = m*64 + lane;
      if (rr < R) A[cg*D_ + j0 + rr] = col[lc][m];
    }
  }
}

// ---------------------------------------------------------------------------
// zung2r: column c of Q = H_0(...H_c(e_c)); one wave per column (needs only
// ~40 VGPRs -> no spill). Branch-free body (tau==0 -> f==0 exactly) and
// v-prefetch: next reflector's 4 loads issue before this iteration's
// shfl-reduce chain, hiding L2 latency under it.
// Epilogue writes the bf16 B^T matrices for both GEMMs:
//   Benc [512][256]: rows 0..255 = Re(Q)^T, rows 256.. = Im(Q)^T
//   Bdec [512][512]: [n][k]: n<256,k<256: ur[k][n]; n<256,k>=256: -ui
//                    n>=256,k<256: ui;             n>=256,k>=256: ur
// ---------------------------------------------------------------------------
__global__ __launch_bounds__(256, 1) void qr_bwd_kernel(
    const float2* __restrict__ A, const float2* __restrict__ tau,
    u16* __restrict__ Benc, u16* __restrict__ Bdec)
{
  const int lane = threadIdx.x & 63;
  const int w = threadIdx.x >> 6;
  const int c = blockIdx.x * 4 + w;          // column 0..255
  __shared__ float2 stau[256];
  if (threadIdx.x < 256) stau[threadIdx.x] = tau[threadIdx.x];
  __syncthreads();

  float2 q[4];
  #pragma unroll
  for (int m = 0; m < 4; ++m) {
    q[m] = make_float2(0.f, 0.f);
    if (m*64 + lane == c) q[m].x = 1.f;      // q = e_c
  }
  float2 araw[4];                            // prefetched raw column i
  #pragma unroll
  for (int m = 0; m < 4; ++m) araw[m] = A[(size_t)c*D_ + m*64 + lane];

  for (int i = c; i >= 0; --i) {
    float2 tt = stau[i];
    float2 v[4];
    #pragma unroll
    for (int m = 0; m < 4; ++m) {
      int r = m*64 + lane;
      v[m] = (r > i) ? araw[m] : ((r == i) ? make_float2(1.f, 0.f)
                                           : make_float2(0.f, 0.f));
    }
    // prefetch next reflector's column (clamped; unused garbage at i==0)
    int inext = (i > 0) ? i - 1 : 0;
    #pragma unroll
    for (int m = 0; m < 4; ++m) araw[m] = A[(size_t)inext*D_ + m*64 + lane];

    float wr = 0.f, wi = 0.f;
    #pragma unroll
    for (int m = 0; m < 4; ++m) {
      wr += v[m].x*q[m].x + v[m].y*q[m].y;   // w += conj(v)*q
      wi += v[m].x*q[m].y - v[m].y*q[m].x;
    }
    #pragma unroll
    for (int s = 32; s; s >>= 1) { wr += __shfl_xor(wr, s); wi += __shfl_xor(wi, s); }
    float fr = tt.x*wr - tt.y*wi;            // f = tau*w  (0 when tau==0)
    float fi = tt.x*wi + tt.y*wr;
    #pragma unroll
    for (int m = 0; m < 4; ++m) {
      q[m].x -= fr*v[m].x - fi*v[m].y;
      q[m].y -= fr*v[m].y + fi*v[m].x;
    }
  }

  #pragma unroll
  for (int m = 0; m < 4; ++m) {
    int r = m*64 + lane;
    u16 qre = f2bf(q[m].x), qim = f2bf(q[m].y), qimn = f2bf(-q[m].y);
    Benc[(size_t)c*D_ + r]              = qre;
    Benc[(size_t)(c+256)*D_ + r]        = qim;
    Bdec[(size_t)c*512 + r]             = qre;
    Bdec[(size_t)c*512 + 256 + r]       = qimn;
    Bdec[(size_t)(c+256)*512 + r]       = qim;
    Bdec[(size_t)(c+256)*512 + 256 + r] = qre;
  }
}

// ---------------------------------------------------------------------------
// x fp32 -> bf16
// ---------------------------------------------------------------------------
__global__ __launch_bounds__(256) void xconv_kernel(
    const float4* __restrict__ x, ushort4* __restrict__ x16)
{
  const size_t n4 = PLANE/4;
  for (size_t i = blockIdx.x*256 + threadIdx.x; i < n4; i += (size_t)2048*256) {
    float4 v = x[i];
    ushort4 o;
    o.x = f2bf(v.x); o.y = f2bf(v.y); o.z = f2bf(v.z); o.w = f2bf(v.w);
    x16[i] = o;
  }
}

// ---------------------------------------------------------------------------
// bf16 MFMA GEMM, 128x128 tile, 4 waves, BK=64, 16x16x32 MFMA.
// A [M][K] bf16 row-major (1 or 2 planes), B supplied transposed [N][K].
// LDS row stride 72 elements (144 B): 16B-aligned, 2-way banks (free).
// ---------------------------------------------------------------------------
#define LDT 72

__global__ __launch_bounds__(256) void encode_gemm(
    const u16* __restrict__ x16, const u16* __restrict__ Bt,
    u16* __restrict__ xer16, u16* __restrict__ xei16)
{
  __shared__ u16 sA[128*LDT];
  __shared__ u16 sB[128*LDT];
  const int tid = threadIdx.x;
  const int lane = tid & 63, w = tid >> 6;
  const int wr = w >> 1, wc = w & 1;
  const int l15 = lane & 15, l4 = lane >> 4;
  const int m0 = blockIdx.x * 128;
  const int n0 = blockIdx.y * 128;
  f32x4 acc[4][4] = {};
  for (int kb = 0; kb < 4; ++kb) {
    #pragma unroll
    for (int i = 0; i < 4; ++i) {
      int chunk = i*256 + tid;
      int row = chunk >> 3, k0 = (chunk & 7) * 8;
      int4 va = *(const int4*)(x16 + (size_t)(m0+row)*D_ + kb*64 + k0);
      int4 vb = *(const int4*)(Bt  + (size_t)(n0+row)*D_ + kb*64 + k0);
      *(int4*)&sA[row*LDT + k0] = va;
      *(int4*)&sB[row*LDT + k0] = vb;
    }
    __syncthreads();
    #pragma unroll
    for (int ks = 0; ks < 2; ++ks) {
      bf16x8 af[4], bb[4];
      #pragma unroll
      for (int mf = 0; mf < 4; ++mf)
        af[mf] = *(const bf16x8*)&sA[(wr*64 + mf*16 + l15)*LDT + ks*32 + l4*8];
      #pragma unroll
      for (int nf = 0; nf < 4; ++nf)
        bb[nf] = *(const bf16x8*)&sB[(wc*64 + nf*16 + l15)*LDT + ks*32 + l4*8];
      #pragma unroll
      for (int mf = 0; mf < 4; ++mf)
        #pragma unroll
        for (int nf = 0; nf < 4; ++nf)
          acc[mf][nf] = __builtin_amdgcn_mfma_f32_16x16x32_bf16(
              af[mf], bb[nf], acc[mf][nf], 0, 0, 0);
    }
    __syncthreads();
  }
  #pragma unroll
  for (int mf = 0; mf < 4; ++mf)
    #pragma unroll
    for (int nf = 0; nf < 4; ++nf)
      #pragma unroll
      for (int r = 0; r < 4; ++r) {
        int row = m0 + wr*64 + mf*16 + l4*4 + r;
        int col = n0 + wc*64 + nf*16 + l15;
        float v = acc[mf][nf][r];
        if (col < 256) xer16[(size_t)row*D_ + col] = f2bf(v);
        else           xei16[(size_t)row*D_ + col - 256] = f2bf(-v);
      }
}

__global__ __launch_bounds__(256) void decode_gemm(
    const u16* __restrict__ hre16, const u16* __restrict__ him16,
    const u16* __restrict__ Bt, float* __restrict__ out)
{
  __shared__ u16 sA[128*LDT];
  __shared__ u16 sB[128*LDT];
  const int tid = threadIdx.x;
  const int lane = tid & 63, w = tid >> 6;
  const int wr = w >> 1, wc = w & 1;
  const int l15 = lane & 15, l4 = lane >> 4;
  const int m0 = blockIdx.x * 128;
  const int n0 = blockIdx.y * 128;
  f32x4 acc[4][4] = {};
  for (int kb = 0; kb < 8; ++kb) {
    const u16* aplane = (kb < 4) ? hre16 : him16;
    const int kk = (kb & 3) * 64;
    #pragma unroll
    for (int i = 0; i < 4; ++i) {
      int chunk = i*256 + tid;
      int row = chunk >> 3, k0 = (chunk & 7) * 8;
      int4 va = *(const int4*)(aplane + (size_t)(m0+row)*D_ + kk + k0);
      int4 vb = *(const int4*)(Bt + (size_t)(n0+row)*512 + kb*64 + k0);
      *(int4*)&sA[row*LDT + k0] = va;
      *(int4*)&sB[row*LDT + k0] = vb;
    }
    __syncthreads();
    #pragma unroll
    for (int ks = 0; ks < 2; ++ks) {
      bf16x8 af[4], bb[4];
      #pragma unroll
      for (int mf = 0; mf < 4; ++mf)
        af[mf] = *(const bf16x8*)&sA[(wr*64 + mf*16 + l15)*LDT + ks*32 + l4*8];
      #pragma unroll
      for (int nf = 0; nf < 4; ++nf)
        bb[nf] = *(const bf16x8*)&sB[(wc*64 + nf*16 + l15)*LDT + ks*32 + l4*8];
      #pragma unroll
      for (int mf = 0; mf < 4; ++mf)
        #pragma unroll
        for (int nf = 0; nf < 4; ++nf)
          acc[mf][nf] = __builtin_amdgcn_mfma_f32_16x16x32_bf16(
              af[mf], bb[nf], acc[mf][nf], 0, 0, 0);
    }
    __syncthreads();
  }
  #pragma unroll
  for (int mf = 0; mf < 4; ++mf)
    #pragma unroll
    for (int nf = 0; nf < 4; ++nf)
      #pragma unroll
      for (int r = 0; r < 4; ++r) {
        int row = m0 + wr*64 + mf*16 + l4*4 + r;
        int col = n0 + wc*64 + nf*16 + l15;
        float v = acc[mf][nf][r];
        if (col < 256) out[(size_t)row*D_ + col] = v;
        else           out[PLANE + (size_t)row*D_ + col - 256] = v;
      }
}

// ---------------------------------------------------------------------------
// Scan with fused coefficient computation. One block per (b,n); thread = d.
// ---------------------------------------------------------------------------
__global__ __launch_bounds__(256) void scan_kernel(
  const float* __restrict__ eps, const float* __restrict__ dt,
  const float* __restrict__ lam_re, const float* __restrict__ lam_im,
  const float* __restrict__ noise_raw,
  const u16* __restrict__ xer16, const u16* __restrict__ xei16,
  u16* __restrict__ hre16, u16* __restrict__ him16)
{
  int bx = blockIdx.x;
  int b = bx >> 9, n = bx & 511;
  int d = threadIdx.x;
  __shared__ float sdt[T_];
  if (d < T_) sdt[d] = dt[b*T_ + d];
  __syncthreads();

  float lr = lam_re[d], li = lam_im[d];
  float lam_r = fmaxf(-log1pf(expf(-lr)), -0.3f);     // -softplus(-x), clamp
  float t0 = lam_r + 1e-12f;
  float sgn = (t0 > 0.f) ? 1.f : ((t0 < 0.f) ? -1.f : 0.f);
  float den_re = lam_r + 1e-8f*sgn, den_im = li;      // lam_safe
  float d2 = den_re*den_re + den_im*den_im;
  float nsc = log1pf(expf(noise_raw[d])) * 0.01f;

  float hr = 0.f, hi = 0.f;
  for (int t = 0; t < T_; ++t) {
    float dtv = sdt[t];
    float er = expf(dtv*lam_r);
    float ai = dtv*li;
    float dre = er*cosf(ai), dim_ = er*sinf(ai);
    float nr = dre - 1.f, ni = dim_;
    float fre = (nr*den_re + ni*den_im)/d2;
    float fim = (ni*den_re - nr*den_im)/d2;
    float ns = sqrtf(fmaxf(dtv, 0.f)) * nsc;
    size_t idx = ((size_t)(b*T_ + t)*N_ + n)*D_ + d;
    float xr = bf2f(xer16[idx]), xi = bf2f(xei16[idx]), ep = eps[idx];
    float br = fre*xr - fim*xi + ep*ns;
    float bi = fre*xi + fim*xr;
    float nr2 = dre*hr - dim_*hi + br;
    float ni2 = dre*hi + dim_*hr + bi;
    hr = nr2; hi = ni2;
    hre16[idx] = f2bf(hr); him16[idx] = f2bf(hi);
  }
}

// ---------------------------------------------------------------------------
extern "C" void kernel_launch(void* const* d_in, const int* in_sizes, int n_in,
                              void* d_out, int out_size, void* d_ws, size_t ws_size,
                              hipStream_t stream)
{
  const float* x         = (const float*)d_in[0];
  const float* dt        = (const float*)d_in[1];
  const float* eps       = (const float*)d_in[2];
  const float* ure_raw   = (const float*)d_in[3];
  const float* uim_raw   = (const float*)d_in[4];
  const float* lam_re    = (const float*)d_in[5];
  const float* lam_im    = (const float*)d_in[6];
  const float* noise_raw = (const float*)d_in[7];
  float* out = (float*)d_out;

  // ws layout (132 MB total):
  //   0       A float2[65536]            512 KB
  //   512K    tau float2[256]
  //   1M      Benc bf16 [512][256]       256 KB
  //   1.5M    Bdec bf16 [512][512]       512 KB
  //   4M      x16 bf16 [M][256]  32 MB   (reused as hre16 after encode)
  //   36M     xer16 32 MB
  //   68M     xei16 32 MB
  //   100M    him16 32 MB
  char* ws = (char*)d_ws;
  float2* A    = (float2*)(ws);
  float2* tau  = (float2*)(ws + 524288);
  u16* Benc    = (u16*)(ws + (1<<20));
  u16* Bdec    = (u16*)(ws + 1572864);
  u16* x16     = (u16*)(ws + ((size_t)4<<20));
  u16* xer16   = (u16*)(ws + ((size_t)36<<20));
  u16* xei16   = (u16*)(ws + ((size_t)68<<20));
  u16* hre16   = x16;
  u16* him16   = (u16*)(ws + ((size_t)100<<20));

  qr_init_kernel<<<64, 1024, 0, stream>>>(ure_raw, uim_raw, A);
  for (int p = 0; p < 8; ++p) {
    qr_panel_kernel<<<1, 256, 0, stream>>>(A, tau, 32*p);
    int nb = 7 - p;
    if (nb > 0) qr_apply_kernel<<<nb, 256, 0, stream>>>(A, tau, 32*p);
  }
  qr_bwd_kernel<<<64, 256, 0, stream>>>(A, tau, Benc, Bdec);
  xconv_kernel<<<2048, 256, 0, stream>>>((const float4*)x, (ushort4*)x16);
  encode_gemm<<<dim3(M_/128, 4), 256, 0, stream>>>(x16, Benc, xer16, xei16);
  scan_kernel<<<B_*N_, 256, 0, stream>>>(eps, dt, lam_re, lam_im, noise_raw,
                                         xer16, xei16, hre16, him16);
  decode_gemm<<<dim3(M_/128, 4), 256, 0, stream>>>(hre16, him16, Bdec, out);
}